// Round 1
// 147.806 us; speedup vs baseline: 1.0700x; 1.0700x over previous
//
#include <hip/hip_runtime.h>
#include <hip/hip_bf16.h>
#include <stdint.h>

// Problem dims (fixed by reference)
#define HH 224
#define WW 224
#define CC 1024
#define BB 256
#define KK (HH*WW)            // 50176
#define EPSILON_F 0.001f
#define LOG2E 1.4426950408889634f
#define INVN (1.0f/50176.0f)
// clip(v,+-2000)/N == clip(v/N, +-2000/N) since 1/N > 0
#define CLAMP_V (2000.0f/50176.0f)

// K-split: 32 chunks of 7 rows. Tile: 256m x 64c, 4 waves (each 64x64).
// grid = 512 blocks (flattened) = 2 blocks/CU.
// XCD swizzle: blocks dispatch round-robin n%8 -> XCD (learn_hip m09). Map so each
// XCD owns 4 k-chunks x all 16 c-tiles: the 16 readers of one 803KB x-slice are
// co-resident on ONE XCD -> slice fetched once into its private L2 (4 slices bf16
// = 3.2MB < 4MB L2). Without this, the 16 readers spread over 8 XCDs and x is
// fetched ~8x (measured FETCH_SIZE 200MB vs 25.7MB ideal).
// B-curves generated once per (c,k) (M-dim not split). Partials -> ws, reduced after
// (R3 lesson: 29.4M atomicAdds serialized the chip; plain stores + reduce instead).
#define KCHUNKS 32
#define ROWS_PER_CHUNK 7
#define STEPS 49              // 7 wb * 7 rows

// 36 elems = 72 B rows: 16-row b128 bank starts (18*r)%32 all distinct -> <=2-way (free)
#define LDS_STRIDE 36

typedef __bf16 bf16x8 __attribute__((ext_vector_type(8)));
typedef float  f32x4  __attribute__((ext_vector_type(4)));

// ---------------- prepass: x fp32 -> bf16 -------------------------------------------------
__global__ __launch_bounds__(256)
void cvt_bf16_kernel(const float* __restrict__ x, __hip_bfloat16* __restrict__ xb, int n8) {
    int i = blockIdx.x * 256 + threadIdx.x;   // one thread per 8 elements
    if (i >= n8) return;
    const float4* p = (const float4*)(x + (size_t)i * 8);
    float4 a = p[0], b = p[1];
    union { __hip_bfloat16 h[8]; uint4 u; } o;
    o.h[0] = (__hip_bfloat16)a.x; o.h[1] = (__hip_bfloat16)a.y;
    o.h[2] = (__hip_bfloat16)a.z; o.h[3] = (__hip_bfloat16)a.w;
    o.h[4] = (__hip_bfloat16)b.x; o.h[5] = (__hip_bfloat16)b.y;
    o.h[6] = (__hip_bfloat16)b.z; o.h[7] = (__hip_bfloat16)b.w;
    *(uint4*)(xb + (size_t)i * 8) = o.u;
}

// ---------------- reduce: out[m][c] = sum_z part[z][m][c] --------------------------------
__global__ __launch_bounds__(256)
void reduce_kernel(const float* __restrict__ part, float* __restrict__ out) {
    int i = blockIdx.x * 256 + threadIdx.x;          // 65536 float4 slots
    const f32x4* p = (const f32x4*)part + i;
    f32x4 s = {0.f, 0.f, 0.f, 0.f};
#pragma unroll
    for (int z = 0; z < KCHUNKS; ++z)
        s += p[(size_t)z * (BB * CC / 4)];
    ((f32x4*)out)[i] = s;
}

// ---------------- main fused curve-gen + GEMM --------------------------------------------
// NOTE: no min-waves arg in __launch_bounds__ (R2: (256,7) spilled the accumulator).
template <bool BF16A, bool PARTIAL>
__global__ __launch_bounds__(256)
void blob_gemm_kernel(const void* __restrict__ xin,
                      const float* __restrict__ pos,
                      const float* __restrict__ sig,
                      const float* __restrict__ cwt,
                      const float* __restrict__ xs,
                      const float* __restrict__ ys,
                      float* __restrict__ dst) {
    // double-buffered tiles
    __shared__ __bf16 As[2][256 * LDS_STRIDE];   // 256 m-rows x 32 k
    __shared__ __bf16 Bs[2][64 * LDS_STRIDE];    // 64 c-rows x 32 k
    __shared__ float  xrow[WW];
    __shared__ float  ycol[ROWS_PER_CHUNK];

    const int tid  = threadIdx.x;
    const int wave = tid >> 6;
    const int lane = tid & 63;

    // ---- XCD-aware swizzle (bijective on 512): xcd = n&7 owns z in [4*xcd, 4*xcd+4) ----
    const int n  = blockIdx.x;
    const int j  = n >> 3;
    const int z  = (n & 7) * 4 + (j >> 4);             // K-chunk (32)
    const int c0 = (j & 15) * 64;                      // N-tile (16)
    const int k0 = z * (ROWS_PER_CHUNK * WW);

    if (tid < WW) xrow[tid] = xs[tid];                 // x_axis
    if (tid >= WW && tid < WW + ROWS_PER_CHUNK)
        ycol[tid - WW] = ys[(z * ROWS_PER_CHUNK + (tid - WW)) * WW];  // y_axis

    // ---- per-thread curve params: one c per thread, one k-octet ----
    const int q   = tid & 3;            // k-octet within 32-wide step
    const int cr0 = tid >> 2;           // 0..63: c-row
    const int c   = c0 + cr0;
    float A2, S2, P0, P1;
    {
        float s  = sig[c];
        float w  = cwt[c];
        float s2 = s * s;
        A2 = w / (6.283185307179586f * s2 + EPSILON_F) * INVN;
        S2 = LOG2E / (2.0f * s2 + EPSILON_F);
        P0 = pos[2 * c];
        P1 = pos[2 * c + 1];
    }

    // A staging: 4 rows per thread (cr0 + 64j), octet q
    const __hip_bfloat16* agb[4];
    const float* agf[4];
#pragma unroll
    for (int jj = 0; jj < 4; ++jj) {
        size_t off = (size_t)(cr0 + 64 * jj) * KK + k0 + q * 8;
        agb[jj] = (const __hip_bfloat16*)xin + off;
        agf[jj] = (const float*)xin + off;
    }
    const int as_w = cr0 * LDS_STRIDE + q * 8;         // + 64j*LDS_STRIDE per row
    const int bs_w = cr0 * LDS_STRIDE + q * 8;

    // wave m-quadrant: wave w covers m rows [64w, 64w+64), all 64 c
    const int wm = wave * 64;
    const int fl = lane & 15;
    const int fk = (lane >> 4) * 8;
    const int ar_off = (wm + fl) * LDS_STRIDE + fk;
    const int br_off = fl * LDS_STRIDE + fk;

    f32x4 acc[4][4];
#pragma unroll
    for (int i = 0; i < 4; ++i)
#pragma unroll
        for (int jj = 0; jj < 4; ++jj) acc[i][jj] = (f32x4){0.f, 0.f, 0.f, 0.f};

    __syncthreads();   // axes ready

    // y-axis values into registers (7 broadcast LDS reads, once)
    float ycolr[ROWS_PER_CHUNK];
#pragma unroll
    for (int r = 0; r < ROWS_PER_CHUNK; ++r) ycolr[r] = ycol[r];

    // ---- Ex for wb=0 + stage step 0 into buffer 0 ----
    float Ex[8];
    {
        float4 xv0 = *(const float4*)(xrow + q * 8);
        float4 xv1 = *(const float4*)(xrow + q * 8 + 4);
        float xv[8] = {xv0.x, xv0.y, xv0.z, xv0.w, xv1.x, xv1.y, xv1.z, xv1.w};
#pragma unroll
        for (int i = 0; i < 8; ++i) {
            float dx = xv[i] - P1;
            Ex[i] = __builtin_amdgcn_exp2f(-(dx * S2 * dx));
        }
        float dy  = ycolr[0] - P0;
        float eyA = __builtin_amdgcn_exp2f(-(dy * S2 * dy)) * A2;
        union { __bf16 h[8]; uint4 u; } cv;
#pragma unroll
        for (int i = 0; i < 8; ++i) {
            float v = Ex[i] * eyA;
            cv.h[i] = (__bf16)fminf(fmaxf(v, -CLAMP_V), CLAMP_V);
        }
        *(uint4*)(&Bs[0][bs_w]) = cv.u;
#pragma unroll
        for (int jj = 0; jj < 4; ++jj) {
            union { __bf16 h[8]; uint4 u; } av;
            if (BF16A) {
                av.u = *(const uint4*)(agb[jj]);
            } else {
                float4 f0 = *(const float4*)(agf[jj]);
                float4 f1 = *(const float4*)(agf[jj] + 4);
                av.h[0] = (__bf16)f0.x; av.h[1] = (__bf16)f0.y;
                av.h[2] = (__bf16)f0.z; av.h[3] = (__bf16)f0.w;
                av.h[4] = (__bf16)f1.x; av.h[5] = (__bf16)f1.y;
                av.h[6] = (__bf16)f1.z; av.h[7] = (__bf16)f1.w;
            }
            *(uint4*)(&As[0][as_w + 64 * jj * LDS_STRIDE]) = av.u;
        }
    }
    __syncthreads();   // buffer 0 ready

    // ---- main loop: step s computes on buf(s&1); stages s+1 into buf(s&1)^1; 1 barrier ----
    int nr = 1, nwb = 0;   // (row, wb) of the step being staged (s+1)
#pragma unroll 2
    for (int s = 0; s < STEPS; ++s) {
        const int cb = s & 1;

        // 1. prefetch next A into registers (longest latency first)
        uint4  pa[4];
        float4 pf0[4], pf1[4];
        if (s < STEPS - 1) {
            const int koff = nr * WW + nwb * 32;   // wave-uniform
            if (BF16A) {
#pragma unroll
                for (int jj = 0; jj < 4; ++jj) pa[jj] = *(const uint4*)(agb[jj] + koff);
            } else {
#pragma unroll
                for (int jj = 0; jj < 4; ++jj) {
                    pf0[jj] = *(const float4*)(agf[jj] + koff);
                    pf1[jj] = *(const float4*)(agf[jj] + koff + 4);
                }
            }
        }

        // 2. fragments + 16 MFMAs on current buffer
        bf16x8 fa[4], fb[4];
#pragma unroll
        for (int i = 0; i < 4; ++i) {
            fa[i] = *(const bf16x8*)(&As[cb][ar_off + i * 16 * LDS_STRIDE]);
            fb[i] = *(const bf16x8*)(&Bs[cb][br_off + i * 16 * LDS_STRIDE]);
        }
#pragma unroll
        for (int mi = 0; mi < 4; ++mi)
#pragma unroll
            for (int ni = 0; ni < 4; ++ni)
                acc[mi][ni] = __builtin_amdgcn_mfma_f32_16x16x32_bf16(
                    fa[mi], fb[ni], acc[mi][ni], 0, 0, 0);

        // 3. stage step s+1 into the other buffer
        if (s < STEPS - 1) {
            if (nr == 0) {   // new wb: refresh Ex (wave-uniform branch)
                float4 xv0 = *(const float4*)(xrow + nwb * 32 + q * 8);
                float4 xv1 = *(const float4*)(xrow + nwb * 32 + q * 8 + 4);
                float xv[8] = {xv0.x, xv0.y, xv0.z, xv0.w, xv1.x, xv1.y, xv1.z, xv1.w};
#pragma unroll
                for (int i = 0; i < 8; ++i) {
                    float dx = xv[i] - P1;
                    Ex[i] = __builtin_amdgcn_exp2f(-(dx * S2 * dx));
                }
            }
            float dy  = ycolr[nr] - P0;
            float eyA = __builtin_amdgcn_exp2f(-(dy * S2 * dy)) * A2;
            union { __bf16 h[8]; uint4 u; } cv;
#pragma unroll
            for (int i = 0; i < 8; ++i) {
                float v = Ex[i] * eyA;
                cv.h[i] = (__bf16)fminf(fmaxf(v, -CLAMP_V), CLAMP_V);
            }
            *(uint4*)(&Bs[cb ^ 1][bs_w]) = cv.u;
#pragma unroll
            for (int jj = 0; jj < 4; ++jj) {
                union { __bf16 h[8]; uint4 u; } av;
                if (BF16A) {
                    av.u = pa[jj];
                } else {
                    av.h[0] = (__bf16)pf0[jj].x; av.h[1] = (__bf16)pf0[jj].y;
                    av.h[2] = (__bf16)pf0[jj].z; av.h[3] = (__bf16)pf0[jj].w;
                    av.h[4] = (__bf16)pf1[jj].x; av.h[5] = (__bf16)pf1[jj].y;
                    av.h[6] = (__bf16)pf1[jj].z; av.h[7] = (__bf16)pf1[jj].w;
                }
                *(uint4*)(&As[cb ^ 1][as_w + 64 * jj * LDS_STRIDE]) = av.u;
            }
            ++nr;
            if (nr == ROWS_PER_CHUNK) { nr = 0; ++nwb; }
        }
        __syncthreads();
    }

    // ---- epilogue: C/D layout col=lane&15, row=(lane>>4)*4+reg ----
    const int orow = (lane >> 4) * 4;
    float* base = PARTIAL ? (dst + (size_t)z * BB * CC) : dst;
#pragma unroll
    for (int mi = 0; mi < 4; ++mi) {
        int m = wm + mi * 16 + orow;
#pragma unroll
        for (int ni = 0; ni < 4; ++ni) {
            int cc = c0 + ni * 16 + fl;
#pragma unroll
            for (int v = 0; v < 4; ++v) {
                if (PARTIAL)
                    base[(size_t)(m + v) * CC + cc] = acc[mi][ni][v];
                else
                    atomicAdd(base + (size_t)(m + v) * CC + cc, acc[mi][ni][v]);
            }
        }
    }
}

extern "C" void kernel_launch(void* const* d_in, const int* in_sizes, int n_in,
                              void* d_out, int out_size, void* d_ws, size_t ws_size,
                              hipStream_t stream) {
    const float* x   = (const float*)d_in[0];
    const float* pos = (const float*)d_in[1];
    const float* sg  = (const float*)d_in[2];
    const float* cw  = (const float*)d_in[3];
    const float* xs  = (const float*)d_in[4];
    const float* ys  = (const float*)d_in[5];
    float* out = (float*)d_out;

    dim3 grid(16 * KCHUNKS);       // 512 blocks (flattened, XCD-swizzled in-kernel)
    const size_t nx   = (size_t)BB * KK;
    const size_t XB   = nx * sizeof(__hip_bfloat16);            // 25.7 MB
    const size_t PART = (size_t)KCHUNKS * BB * CC * 4;          // 33.6 MB
    const int n8 = (int)(nx / 8);

    if (ws_size >= XB + PART) {
        __hip_bfloat16* xb = (__hip_bfloat16*)d_ws;
        float* part = (float*)((char*)d_ws + XB);
        cvt_bf16_kernel<<<(n8 + 255) / 256, 256, 0, stream>>>(x, xb, n8);
        blob_gemm_kernel<true, true><<<grid, 256, 0, stream>>>(xb, pos, sg, cw, xs, ys, part);
        reduce_kernel<<<BB * CC / 4 / 256, 256, 0, stream>>>(part, out);
    } else if (ws_size >= PART) {
        float* part = (float*)d_ws;
        blob_gemm_kernel<false, true><<<grid, 256, 0, stream>>>(x, pos, sg, cw, xs, ys, part);
        reduce_kernel<<<BB * CC / 4 / 256, 256, 0, stream>>>(part, out);
    } else if (ws_size >= XB) {
        __hip_bfloat16* xb = (__hip_bfloat16*)d_ws;
        hipMemsetAsync(out, 0, (size_t)BB * CC * sizeof(float), stream);
        cvt_bf16_kernel<<<(n8 + 255) / 256, 256, 0, stream>>>(x, xb, n8);
        blob_gemm_kernel<true, false><<<grid, 256, 0, stream>>>(xb, pos, sg, cw, xs, ys, out);
    } else {
        hipMemsetAsync(out, 0, (size_t)BB * CC * sizeof(float), stream);
        blob_gemm_kernel<false, false><<<grid, 256, 0, stream>>>(x, pos, sg, cw, xs, ys, out);
    }
}